// Round 1
// baseline (332.823 us; speedup 1.0000x reference)
//
#include <hip/hip_runtime.h>
#include <hip/hip_bf16.h>
#include <math.h>

// Problem constants (fixed by the reference)
#define NN 129
#define FF 262144
#define EE 16384
#define CHUNKS 32
#define CHUNK (FF / CHUNKS)   // 8192 floats per block

// ---------------------------------------------------------------------------
// Kernel 1: big matvec xw[r] = dot(x[r,:], W)  (partials, deterministic), plus
// one extra block computing per-channel deg -> dinv (doesn't need xw).
// ---------------------------------------------------------------------------
__global__ __launch_bounds__(256) void k_matvec(
    const float* __restrict__ x, const float* __restrict__ W,
    const int* __restrict__ eidx, const float* __restrict__ eattr,
    double* __restrict__ partial /* [NN*CHUNKS] */,
    double* __restrict__ dinv_out /* [3*NN] */)
{
    const int b = blockIdx.x;
    const int tid = threadIdx.x;

    __shared__ double ws4[4];
    __shared__ double deg[3][NN];

    if (b < NN * CHUNKS) {
        const int r = b / CHUNKS, ch = b % CHUNKS;
        const float4* xp = (const float4*)(x + (size_t)r * FF + (size_t)ch * CHUNK);
        const float4* wp = (const float4*)(W + (size_t)ch * CHUNK);
        double acc = 0.0;
#pragma unroll
        for (int i = 0; i < CHUNK / (256 * 4); ++i) {   // 8 iters
            float4 xv = xp[tid + i * 256];
            float4 wv = wp[tid + i * 256];
            acc += (double)xv.x * (double)wv.x + (double)xv.y * (double)wv.y
                 + (double)xv.z * (double)wv.z + (double)xv.w * (double)wv.w;
        }
        // wave (64-lane) tree reduce, then cross-wave via LDS — deterministic
        for (int off = 32; off > 0; off >>= 1) acc += __shfl_down(acc, off, 64);
        const int wave = tid >> 6, lane = tid & 63;
        if (lane == 0) ws4[wave] = acc;
        __syncthreads();
        if (tid == 0) partial[b] = (ws4[0] + ws4[1]) + (ws4[2] + ws4[3]);
    } else {
        // degree block: deg[c][j] = 1 (self loop) + sum_{e: col[e]==j} ew[e][c]
        for (int i = tid; i < 3 * NN; i += 256) deg[i / NN][i % NN] = 1.0;
        __syncthreads();
        const int* col = eidx + EE;
        for (int e = tid; e < EE; e += 256) {
            const int cl = col[e];
#pragma unroll
            for (int c = 0; c < 3; ++c)
                unsafeAtomicAdd(&deg[c][cl], (double)eattr[e * 3 + c]);
        }
        __syncthreads();
        for (int i = tid; i < 3 * NN; i += 256) {
            double d = deg[i / NN][i % NN];
            dinv_out[i] = (d > 0.0) ? 1.0 / sqrt(d) : 0.0;
        }
    }
}

// ---------------------------------------------------------------------------
// Kernel 2: everything else, one block, fp64 in LDS.
// ---------------------------------------------------------------------------
__global__ __launch_bounds__(256) void k_rest(
    const int* __restrict__ eidx, const float* __restrict__ eattr,
    const double* __restrict__ partial, const double* __restrict__ dinvg,
    const float* __restrict__ b1, const float* __restrict__ W2, const float* __restrict__ b2,
    const float* __restrict__ c1w, const float* __restrict__ c1b,
    const float* __restrict__ c2w, const float* __restrict__ c2b,
    const float* __restrict__ f1W, const float* __restrict__ f1b,
    const float* __restrict__ f2W, const float* __restrict__ f2b,
    const float* __restrict__ f3W, const float* __restrict__ f3b,
    float* __restrict__ out)
{
    __shared__ double xw[NN];
    __shared__ double dinv[3][NN];
    __shared__ double h1[3][NN], h2[3][NN];
    __shared__ double hp[4][3][NN];          // per-wave privatized accumulators
    __shared__ double z0[3][NN], z1[3][NN];  // sorted h1/h2
    __shared__ int    rnk[3][NN];
    __shared__ double c1o[3][3][127];
    __shared__ double p1o[3][3][125];
    __shared__ double c2o[3][123];
    __shared__ double allx[363];
    __shared__ double fc1o[32], fc2o[6];

    const int tid = threadIdx.x;
    const int wave = tid >> 6;
    const int* row = eidx;
    const int* col = eidx + EE;

    // xw[j] = sum of 32 chunk partials (fixed order -> deterministic)
    for (int j = tid; j < NN; j += 256) {
        double s = 0.0;
        for (int k = 0; k < CHUNKS; ++k) s += partial[j * CHUNKS + k];
        xw[j] = s;
    }
    for (int i = tid; i < 3 * NN; i += 256) dinv[i / NN][i % NN] = dinvg[i];
    for (int i = tid; i < 4 * 3 * NN; i += 256) ((double*)hp)[i] = 0.0;
    __syncthreads();

    // ---- GCN layer 1 (all 3 channels): h1[c][j] = sum norm*xw[row] + self + b1
    for (int e = tid; e < EE; e += 256) {
        const int r = row[e], cl = col[e];
        const double xwr = xw[r];
#pragma unroll
        for (int c = 0; c < 3; ++c) {
            const double nw = dinv[c][r] * (double)eattr[e * 3 + c] * dinv[c][cl];
            unsafeAtomicAdd(&hp[wave][c][cl], nw * xwr);
        }
    }
    __syncthreads();
    const double bb1 = (double)b1[0];
    for (int i = tid; i < 3 * NN; i += 256) {
        const int c = i / NN, j = i % NN;
        double s = dinv[c][j] * dinv[c][j] * xw[j] + bb1;  // self loop (weight 1)
#pragma unroll
        for (int w = 0; w < 4; ++w) s += hp[w][c][j];
        h1[c][j] = s;
    }
    __syncthreads();
    for (int i = tid; i < 4 * 3 * NN; i += 256) ((double*)hp)[i] = 0.0;
    __syncthreads();

    // ---- GCN layer 2: xw2 = h1 * w2 (scalar); same dinv (same edge weights)
    const double w2 = (double)W2[0], bb2 = (double)b2[0];
    for (int e = tid; e < EE; e += 256) {
        const int r = row[e], cl = col[e];
#pragma unroll
        for (int c = 0; c < 3; ++c) {
            const double nw = dinv[c][r] * (double)eattr[e * 3 + c] * dinv[c][cl];
            unsafeAtomicAdd(&hp[wave][c][cl], nw * (h1[c][r] * w2));
        }
    }
    __syncthreads();
    for (int i = tid; i < 3 * NN; i += 256) {
        const int c = i / NN, j = i % NN;
        double s = dinv[c][j] * dinv[c][j] * (h1[c][j] * w2) + bb2;
#pragma unroll
        for (int w = 0; w < 4; ++w) s += hp[w][c][j];
        h2[c][j] = s;
    }
    __syncthreads();

    // ---- SortPool: stable argsort of -h2 (descending, ties by index), k = N
    for (int i = tid; i < 3 * NN; i += 256) {
        const int c = i / NN, j = i % NN;
        const double v = h2[c][j];
        int rk = 0;
        for (int q = 0; q < NN; ++q) {
            const double u = h2[c][q];
            rk += (u > v) || (u == v && q < j);
        }
        rnk[c][j] = rk;
    }
    __syncthreads();
    for (int i = tid; i < 3 * NN; i += 256) {
        const int c = i / NN, j = i % NN;
        const int rk = rnk[c][j];
        z0[c][rk] = h1[c][j];
        z1[c][rk] = h2[c][j];
    }
    __syncthreads();

    // ---- conv1 (in=2,out=3,k=3, VALID) -> 127
    for (int i = tid; i < 3 * 3 * 127; i += 256) {
        const int c = i / (3 * 127), rem = i % (3 * 127), o = rem / 127, p = rem % 127;
        double s = (double)c1b[o];
#pragma unroll
        for (int k = 0; k < 3; ++k) {
            s += (double)c1w[(o * 2 + 0) * 3 + k] * z0[c][p + k];
            s += (double)c1w[(o * 2 + 1) * 3 + k] * z1[c][p + k];
        }
        c1o[c][o][p] = s;
    }
    __syncthreads();
    // maxpool3 stride1 -> 125
    for (int i = tid; i < 3 * 3 * 125; i += 256) {
        const int c = i / (3 * 125), rem = i % (3 * 125), o = rem / 125, p = rem % 125;
        p1o[c][o][p] = fmax(c1o[c][o][p], fmax(c1o[c][o][p + 1], c1o[c][o][p + 2]));
    }
    __syncthreads();
    // conv2 (in=3,out=1,k=3) -> 123
    for (int i = tid; i < 3 * 123; i += 256) {
        const int c = i / 123, p = i % 123;
        double s = (double)c2b[0];
#pragma unroll
        for (int ic = 0; ic < 3; ++ic)
#pragma unroll
            for (int k = 0; k < 3; ++k)
                s += (double)c2w[ic * 3 + k] * p1o[c][ic][p + k];
        c2o[c][p] = s;
    }
    __syncthreads();
    // maxpool3 -> 121 ; concat channels -> allx[363]
    for (int i = tid; i < 3 * 121; i += 256) {
        const int c = i / 121, p = i % 121;
        allx[c * 121 + p] = fmax(c2o[c][p], fmax(c2o[c][p + 1], c2o[c][p + 2]));
    }
    __syncthreads();

    // ---- fc1: 363 -> 32, ELU. 8 lanes per output (aligned sub-groups of 8).
    {
        const int j = tid >> 3, t = tid & 7;
        double s = 0.0;
        for (int i = t; i < 363; i += 8) s += allx[i] * (double)f1W[i * 32 + j];
        s += __shfl_down(s, 4, 8);
        s += __shfl_down(s, 2, 8);
        s += __shfl_down(s, 1, 8);
        if (t == 0) {
            s += (double)f1b[j];
            fc1o[j] = (s > 0.0) ? s : expm1(s);
        }
    }
    __syncthreads();
    // ---- fc2: 32 -> 6, ELU
    if (tid < 6) {
        double s = (double)f2b[tid];
        for (int i = 0; i < 32; ++i) s += fc1o[i] * (double)f2W[i * 6 + tid];
        fc2o[tid] = (s > 0.0) ? s : expm1(s);
    }
    __syncthreads();
    // ---- fc3: 6 -> 2
    if (tid < 2) {
        double s = (double)f3b[tid];
        for (int i = 0; i < 6; ++i) s += fc2o[i] * (double)f3W[i * 2 + tid];
        out[tid] = (float)s;
    }
}

extern "C" void kernel_launch(void* const* d_in, const int* in_sizes, int n_in,
                              void* d_out, int out_size, void* d_ws, size_t ws_size,
                              hipStream_t stream) {
    const float* x    = (const float*)d_in[0];
    const int*   eidx = (const int*)d_in[1];
    const float* eattr= (const float*)d_in[2];
    const float* g1W  = (const float*)d_in[3];
    const float* g1b  = (const float*)d_in[4];
    const float* g2W  = (const float*)d_in[5];
    const float* g2b  = (const float*)d_in[6];
    const float* c1w  = (const float*)d_in[7];
    const float* c1b  = (const float*)d_in[8];
    const float* c2w  = (const float*)d_in[9];
    const float* c2b  = (const float*)d_in[10];
    const float* f1W  = (const float*)d_in[11];
    const float* f1b  = (const float*)d_in[12];
    const float* f2W  = (const float*)d_in[13];
    const float* f2b  = (const float*)d_in[14];
    const float* f3W  = (const float*)d_in[15];
    const float* f3b  = (const float*)d_in[16];
    float* out = (float*)d_out;

    double* partial = (double*)d_ws;              // [NN*CHUNKS] = 4128 doubles
    double* dinvg   = partial + NN * CHUNKS;      // [3*NN] doubles

    k_matvec<<<NN * CHUNKS + 1, 256, 0, stream>>>(x, g1W, eidx, eattr, partial, dinvg);
    k_rest<<<1, 256, 0, stream>>>(eidx, eattr, partial, dinvg,
                                  g1b, g2W, g2b, c1w, c1b, c2w, c2b,
                                  f1W, f1b, f2W, f2b, f3W, f3b, out);
}

// Round 2
// 265.957 us; speedup vs baseline: 1.2514x; 1.2514x over previous
//
#include <hip/hip_runtime.h>
#include <hip/hip_bf16.h>
#include <math.h>

// Problem constants (fixed by the reference)
#define NN 129
#define FF 262144
#define EE 16384
#define CHUNKS 32
#define CHUNK (FF / CHUNKS)   // 8192 floats per matvec block
#define NAGG 16               // aggregation blocks
#define EPB (EE / NAGG)       // 1024 edges per aggregation block

// ws layout (doubles)
#define OFF_PARTIAL 0                       // [NN*CHUNKS] = 4128
#define OFF_DEGP    (OFF_PARTIAL + NN*CHUNKS)      // [NAGG*3*NN] = 6192
#define OFF_DINV    (OFF_DEGP + NAGG*3*NN)         // [3*NN] = 387
#define OFF_XW      (OFF_DINV + 3*NN)              // [NN]
#define OFF_H1P     (OFF_XW + NN)                  // [NAGG*3*NN]
#define OFF_H1      (OFF_H1P + NAGG*3*NN)          // [3*NN]
#define OFF_H2P     (OFF_H1 + 3*NN)                // [NAGG*3*NN]

// ---------------------------------------------------------------------------
// K1: matvec partials (4128 blocks) + 16 blocks of per-block degree partials
// (overlapped with the matvec — they cost nothing extra).
// ---------------------------------------------------------------------------
__global__ __launch_bounds__(256) void k_matvec(
    const float* __restrict__ x, const float* __restrict__ W,
    const int* __restrict__ eidx, const float* __restrict__ eattr,
    double* __restrict__ ws)
{
    const int b = blockIdx.x;
    const int tid = threadIdx.x;
    const int wave = tid >> 6, lane = tid & 63;

    __shared__ double ws4[4];
    __shared__ double dp[4][3][NN];

    if (b < NN * CHUNKS) {
        const int r = b / CHUNKS, ch = b % CHUNKS;
        const float4* xp = (const float4*)(x + (size_t)r * FF + (size_t)ch * CHUNK);
        const float4* wp = (const float4*)(W + (size_t)ch * CHUNK);
        double acc = 0.0;
#pragma unroll
        for (int i = 0; i < CHUNK / (256 * 4); ++i) {   // 8 iters
            float4 xv = xp[tid + i * 256];
            float4 wv = wp[tid + i * 256];
            acc += (double)xv.x * (double)wv.x + (double)xv.y * (double)wv.y
                 + (double)xv.z * (double)wv.z + (double)xv.w * (double)wv.w;
        }
        for (int off = 32; off > 0; off >>= 1) acc += __shfl_down(acc, off, 64);
        if (lane == 0) ws4[wave] = acc;
        __syncthreads();
        if (tid == 0) ws[OFF_PARTIAL + b] = (ws4[0] + ws4[1]) + (ws4[2] + ws4[3]);
    } else {
        const int bb = b - NN * CHUNKS;                 // [0, NAGG)
        for (int i = tid; i < 4 * 3 * NN; i += 256) ((double*)dp)[i] = 0.0;
        __syncthreads();
        const int* col = eidx + EE;
#pragma unroll
        for (int i = 0; i < EPB / 256; ++i) {           // 4 iters
            const int e = bb * EPB + i * 256 + tid;
            const int cl = col[e];
#pragma unroll
            for (int c = 0; c < 3; ++c)
                unsafeAtomicAdd(&dp[wave][c][cl], (double)eattr[e * 3 + c]);
        }
        __syncthreads();
        for (int i = tid; i < 3 * NN; i += 256)
            ws[OFF_DEGP + bb * (3 * NN) + i] =
                (dp[0][0][0 * 0] , ((dp[0][i / NN][i % NN] + dp[1][i / NN][i % NN])
                                  + (dp[2][i / NN][i % NN] + dp[3][i / NN][i % NN])));
    }
}

// ---------------------------------------------------------------------------
// K2 (grid 2): block 0 reduces matvec partials -> xw; block 1 reduces degree
// partials -> dinv = deg^-1/2 (deg includes the self-loop weight 1).
// ---------------------------------------------------------------------------
__global__ __launch_bounds__(256) void k_reduce1(double* __restrict__ ws)
{
    const int tid = threadIdx.x;
    if (blockIdx.x == 0) {
        for (int j = tid; j < NN; j += 256) {
            double s = 0.0;
#pragma unroll
            for (int k = 0; k < CHUNKS; ++k) s += ws[OFF_PARTIAL + j * CHUNKS + k];
            ws[OFF_XW + j] = s;
        }
    } else {
        for (int v = tid; v < 3 * NN; v += 256) {
            double d = 1.0;                              // self loop
#pragma unroll
            for (int b = 0; b < NAGG; ++b) d += ws[OFF_DEGP + b * (3 * NN) + v];
            ws[OFF_DINV + v] = (d > 0.0) ? 1.0 / sqrt(d) : 0.0;
        }
    }
}

// ---------------------------------------------------------------------------
// K3 (grid NAGG): layer-1 edge aggregation -> deterministic block partials.
// ---------------------------------------------------------------------------
__global__ __launch_bounds__(256) void k_agg1(
    const int* __restrict__ eidx, const float* __restrict__ eattr,
    double* __restrict__ ws)
{
    const int b = blockIdx.x, tid = threadIdx.x, wave = tid >> 6;
    __shared__ double sxw[NN];
    __shared__ double sdinv[3][NN];
    __shared__ double hp[4][3][NN];
    for (int i = tid; i < NN; i += 256) sxw[i] = ws[OFF_XW + i];
    for (int i = tid; i < 3 * NN; i += 256) ((double*)sdinv)[i] = ws[OFF_DINV + i];
    for (int i = tid; i < 4 * 3 * NN; i += 256) ((double*)hp)[i] = 0.0;
    __syncthreads();
    const int* row = eidx;
    const int* col = eidx + EE;
#pragma unroll
    for (int i = 0; i < EPB / 256; ++i) {
        const int e = b * EPB + i * 256 + tid;
        const int r = row[e], cl = col[e];
        const double xwr = sxw[r];
#pragma unroll
        for (int c = 0; c < 3; ++c) {
            const double nw = sdinv[c][r] * (double)eattr[e * 3 + c] * sdinv[c][cl];
            unsafeAtomicAdd(&hp[wave][c][cl], nw * xwr);
        }
    }
    __syncthreads();
    for (int i = tid; i < 3 * NN; i += 256) {
        const int c = i / NN, j = i % NN;
        ws[OFF_H1P + b * (3 * NN) + i] =
            (hp[0][c][j] + hp[1][c][j]) + (hp[2][c][j] + hp[3][c][j]);
    }
}

// ---------------------------------------------------------------------------
// K4 (grid 1): reduce layer-1 partials + self term + bias -> h1 (global).
// ---------------------------------------------------------------------------
__global__ __launch_bounds__(256) void k_h1(
    const float* __restrict__ b1, double* __restrict__ ws)
{
    const int tid = threadIdx.x;
    const double bb1 = (double)b1[0];
    for (int i = tid; i < 3 * NN; i += 256) {
        const int j = i % NN;
        const double dv = ws[OFF_DINV + i];
        double s = dv * dv * ws[OFF_XW + j] + bb1;
#pragma unroll
        for (int b = 0; b < NAGG; ++b) s += ws[OFF_H1P + b * (3 * NN) + i];
        ws[OFF_H1 + i] = s;
    }
}

// ---------------------------------------------------------------------------
// K5 (grid NAGG): layer-2 edge aggregation (input h1[c]*w2) -> block partials.
// ---------------------------------------------------------------------------
__global__ __launch_bounds__(256) void k_agg2(
    const int* __restrict__ eidx, const float* __restrict__ eattr,
    const float* __restrict__ W2, double* __restrict__ ws)
{
    const int b = blockIdx.x, tid = threadIdx.x, wave = tid >> 6;
    __shared__ double sh1[3][NN];
    __shared__ double sdinv[3][NN];
    __shared__ double hp[4][3][NN];
    const double w2 = (double)W2[0];
    for (int i = tid; i < 3 * NN; i += 256) {
        ((double*)sh1)[i] = ws[OFF_H1 + i];
        ((double*)sdinv)[i] = ws[OFF_DINV + i];
    }
    for (int i = tid; i < 4 * 3 * NN; i += 256) ((double*)hp)[i] = 0.0;
    __syncthreads();
    const int* row = eidx;
    const int* col = eidx + EE;
#pragma unroll
    for (int i = 0; i < EPB / 256; ++i) {
        const int e = b * EPB + i * 256 + tid;
        const int r = row[e], cl = col[e];
#pragma unroll
        for (int c = 0; c < 3; ++c) {
            const double nw = sdinv[c][r] * (double)eattr[e * 3 + c] * sdinv[c][cl];
            unsafeAtomicAdd(&hp[wave][c][cl], nw * (sh1[c][r] * w2));
        }
    }
    __syncthreads();
    for (int i = tid; i < 3 * NN; i += 256) {
        const int c = i / NN, j = i % NN;
        ws[OFF_H2P + b * (3 * NN) + i] =
            (hp[0][c][j] + hp[1][c][j]) + (hp[2][c][j] + hp[3][c][j]);
    }
}

// ---------------------------------------------------------------------------
// K6 (grid 1): finalize h2, SortPool, convs, FCs. Small LDS ops only.
// ---------------------------------------------------------------------------
__global__ __launch_bounds__(256) void k_final(
    const double* __restrict__ ws,
    const float* __restrict__ W2, const float* __restrict__ b2,
    const float* __restrict__ c1w, const float* __restrict__ c1b,
    const float* __restrict__ c2w, const float* __restrict__ c2b,
    const float* __restrict__ f1W, const float* __restrict__ f1b,
    const float* __restrict__ f2W, const float* __restrict__ f2b,
    const float* __restrict__ f3W, const float* __restrict__ f3b,
    float* __restrict__ out)
{
    __shared__ double h1[3][NN], h2[3][NN];
    __shared__ double z0[3][NN], z1[3][NN];
    __shared__ int    rnk[3][NN];
    __shared__ double c1o[3][3][127];
    __shared__ double p1o[3][3][125];
    __shared__ double c2o[3][123];
    __shared__ double allx[363];
    __shared__ double fc1o[32], fc2o[6];

    const int tid = threadIdx.x;
    const double w2 = (double)W2[0], bb2 = (double)b2[0];

    for (int i = tid; i < 3 * NN; i += 256) {
        const double hv = ws[OFF_H1 + i];
        ((double*)h1)[i] = hv;
        const double dv = ws[OFF_DINV + i];
        double s = dv * dv * (hv * w2) + bb2;
#pragma unroll
        for (int b = 0; b < NAGG; ++b) s += ws[OFF_H2P + b * (3 * NN) + i];
        ((double*)h2)[i] = s;
    }
    __syncthreads();

    // SortPool: stable argsort of -h2 (descending, ties by index), k = N
    for (int i = tid; i < 3 * NN; i += 256) {
        const int c = i / NN, j = i % NN;
        const double v = h2[c][j];
        int rk = 0;
        for (int q = 0; q < NN; ++q) {
            const double u = h2[c][q];
            rk += (u > v) || (u == v && q < j);
        }
        rnk[c][j] = rk;
    }
    __syncthreads();
    for (int i = tid; i < 3 * NN; i += 256) {
        const int c = i / NN, j = i % NN;
        const int rk = rnk[c][j];
        z0[c][rk] = h1[c][j];
        z1[c][rk] = h2[c][j];
    }
    __syncthreads();

    // conv1 (in=2,out=3,k=3, VALID) -> 127
    for (int i = tid; i < 3 * 3 * 127; i += 256) {
        const int c = i / (3 * 127), rem = i % (3 * 127), o = rem / 127, p = rem % 127;
        double s = (double)c1b[o];
#pragma unroll
        for (int k = 0; k < 3; ++k) {
            s += (double)c1w[(o * 2 + 0) * 3 + k] * z0[c][p + k];
            s += (double)c1w[(o * 2 + 1) * 3 + k] * z1[c][p + k];
        }
        c1o[c][o][p] = s;
    }
    __syncthreads();
    for (int i = tid; i < 3 * 3 * 125; i += 256) {
        const int c = i / (3 * 125), rem = i % (3 * 125), o = rem / 125, p = rem % 125;
        p1o[c][o][p] = fmax(c1o[c][o][p], fmax(c1o[c][o][p + 1], c1o[c][o][p + 2]));
    }
    __syncthreads();
    for (int i = tid; i < 3 * 123; i += 256) {
        const int c = i / 123, p = i % 123;
        double s = (double)c2b[0];
#pragma unroll
        for (int ic = 0; ic < 3; ++ic)
#pragma unroll
            for (int k = 0; k < 3; ++k)
                s += (double)c2w[ic * 3 + k] * p1o[c][ic][p + k];
        c2o[c][p] = s;
    }
    __syncthreads();
    for (int i = tid; i < 3 * 121; i += 256) {
        const int c = i / 121, p = i % 121;
        allx[c * 121 + p] = fmax(c2o[c][p], fmax(c2o[c][p + 1], c2o[c][p + 2]));
    }
    __syncthreads();

    // fc1: 363 -> 32, ELU (8 lanes per output)
    {
        const int j = tid >> 3, t = tid & 7;
        double s = 0.0;
        for (int i = t; i < 363; i += 8) s += allx[i] * (double)f1W[i * 32 + j];
        s += __shfl_down(s, 4, 8);
        s += __shfl_down(s, 2, 8);
        s += __shfl_down(s, 1, 8);
        if (t == 0) {
            s += (double)f1b[j];
            fc1o[j] = (s > 0.0) ? s : expm1(s);
        }
    }
    __syncthreads();
    if (tid < 6) {
        double s = (double)f2b[tid];
        for (int i = 0; i < 32; ++i) s += fc1o[i] * (double)f2W[i * 6 + tid];
        fc2o[tid] = (s > 0.0) ? s : expm1(s);
    }
    __syncthreads();
    if (tid < 2) {
        double s = (double)f3b[tid];
        for (int i = 0; i < 6; ++i) s += fc2o[i] * (double)f3W[i * 2 + tid];
        out[tid] = (float)s;
    }
}

extern "C" void kernel_launch(void* const* d_in, const int* in_sizes, int n_in,
                              void* d_out, int out_size, void* d_ws, size_t ws_size,
                              hipStream_t stream) {
    const float* x    = (const float*)d_in[0];
    const int*   eidx = (const int*)d_in[1];
    const float* eattr= (const float*)d_in[2];
    const float* g1W  = (const float*)d_in[3];
    const float* g1b  = (const float*)d_in[4];
    const float* g2W  = (const float*)d_in[5];
    const float* g2b  = (const float*)d_in[6];
    const float* c1w  = (const float*)d_in[7];
    const float* c1b  = (const float*)d_in[8];
    const float* c2w  = (const float*)d_in[9];
    const float* c2b  = (const float*)d_in[10];
    const float* f1W  = (const float*)d_in[11];
    const float* f1b  = (const float*)d_in[12];
    const float* f2W  = (const float*)d_in[13];
    const float* f2b  = (const float*)d_in[14];
    const float* f3W  = (const float*)d_in[15];
    const float* f3b  = (const float*)d_in[16];
    float* out = (float*)d_out;
    double* ws = (double*)d_ws;

    k_matvec<<<NN * CHUNKS + NAGG, 256, 0, stream>>>(x, g1W, eidx, eattr, ws);
    k_reduce1<<<2, 256, 0, stream>>>(ws);
    k_agg1<<<NAGG, 256, 0, stream>>>(eidx, eattr, ws);
    k_h1<<<1, 256, 0, stream>>>(g1b, ws);
    k_agg2<<<NAGG, 256, 0, stream>>>(eidx, eattr, g2W, ws);
    k_final<<<1, 256, 0, stream>>>(ws, g2W, g2b, c1w, c1b, c2w, c2b,
                                   f1W, f1b, f2W, f2b, f3W, f3b, out);
}

// Round 3
// 265.172 us; speedup vs baseline: 1.2551x; 1.0030x over previous
//
#include <hip/hip_runtime.h>
#include <hip/hip_bf16.h>
#include <math.h>

// Problem constants (fixed by the reference)
#define NN 129
#define FF 262144
#define EE 16384
#define CHUNKS 32
#define CHUNK (FF / CHUNKS)   // 8192 floats per matvec block
#define NB 16                 // tail-kernel blocks (== degree partial blocks)
#define EPB (EE / NB)         // 1024 edges per block

// ws layout (doubles)
#define OFF_PARTIAL 0                              // [NN*CHUNKS] = 4128
#define OFF_DEGP    (OFF_PARTIAL + NN*CHUNKS)      // [NB*3*NN]
#define OFF_H1P     (OFF_DEGP + NB*3*NN)           // [NB*3*NN]
#define OFF_H2P     (OFF_H1P + NB*3*NN)            // [NB*3*NN]
#define OFF_BAR     (OFF_H2P + NB*3*NN)            // 2 uints (in a double slot)

// ---------------------------------------------------------------------------
// K1: matvec partials (4128 blocks) + NB blocks of per-block degree partials
// (overlapped with the matvec). Block NN*CHUNKS also zeroes the K2 barriers.
// ---------------------------------------------------------------------------
__global__ __launch_bounds__(256) void k_matvec(
    const float* __restrict__ x, const float* __restrict__ W,
    const int* __restrict__ eidx, const float* __restrict__ eattr,
    double* __restrict__ ws)
{
    const int b = blockIdx.x;
    const int tid = threadIdx.x;
    const int wave = tid >> 6, lane = tid & 63;

    __shared__ double ws4[4];
    __shared__ double dp[4][3][NN];

    if (b < NN * CHUNKS) {
        const int r = b / CHUNKS, ch = b % CHUNKS;
        const float4* xp = (const float4*)(x + (size_t)r * FF + (size_t)ch * CHUNK);
        const float4* wp = (const float4*)(W + (size_t)ch * CHUNK);
        double acc = 0.0;
#pragma unroll
        for (int i = 0; i < CHUNK / (256 * 4); ++i) {   // 8 iters
            float4 xv = xp[tid + i * 256];
            float4 wv = wp[tid + i * 256];
            acc += (double)xv.x * (double)wv.x + (double)xv.y * (double)wv.y
                 + (double)xv.z * (double)wv.z + (double)xv.w * (double)wv.w;
        }
        for (int off = 32; off > 0; off >>= 1) acc += __shfl_down(acc, off, 64);
        if (lane == 0) ws4[wave] = acc;
        __syncthreads();
        if (tid == 0) ws[OFF_PARTIAL + b] = (ws4[0] + ws4[1]) + (ws4[2] + ws4[3]);
    } else {
        const int bb = b - NN * CHUNKS;                 // [0, NB)
        if (bb == 0 && tid == 0) {
            unsigned* bar = (unsigned*)(ws + OFF_BAR);
            __hip_atomic_store(&bar[0], 0u, __ATOMIC_RELAXED, __HIP_MEMORY_SCOPE_AGENT);
            __hip_atomic_store(&bar[1], 0u, __ATOMIC_RELAXED, __HIP_MEMORY_SCOPE_AGENT);
        }
        for (int i = tid; i < 4 * 3 * NN; i += 256) ((double*)dp)[i] = 0.0;
        __syncthreads();
        const int* col = eidx + EE;
#pragma unroll
        for (int i = 0; i < EPB / 256; ++i) {           // 4 iters
            const int e = bb * EPB + i * 256 + tid;
            const int cl = col[e];
#pragma unroll
            for (int c = 0; c < 3; ++c)
                unsafeAtomicAdd(&dp[wave][c][cl], (double)eattr[e * 3 + c]);
        }
        __syncthreads();
        for (int i = tid; i < 3 * NN; i += 256) {
            const int c = i / NN, j = i % NN;
            ws[OFF_DEGP + bb * (3 * NN) + i] =
                (dp[0][c][j] + dp[1][c][j]) + (dp[2][c][j] + dp[3][c][j]);
        }
    }
}

// ---------------------------------------------------------------------------
// Device-scope barrier for NB co-resident blocks (counters zeroed by K1).
// ---------------------------------------------------------------------------
__device__ __forceinline__ void gbar(unsigned* bar, int idx) {
    __syncthreads();
    if (threadIdx.x == 0) {
        __threadfence();
        __hip_atomic_fetch_add(&bar[idx], 1u, __ATOMIC_ACQ_REL, __HIP_MEMORY_SCOPE_AGENT);
        while (__hip_atomic_load(&bar[idx], __ATOMIC_ACQUIRE, __HIP_MEMORY_SCOPE_AGENT) < (unsigned)NB)
            __builtin_amdgcn_s_sleep(1);
        __threadfence();
    }
    __syncthreads();
}

// ---------------------------------------------------------------------------
// K2 (NB blocks, manual grid barriers): entire rest of the network.
// Phase 0: every block redundantly reduces xw + dinv into LDS (no sync needed).
// Phase 1: layer-1 edge aggregation -> block partials.  [barrier 0]
// Phase 2: every block redundantly reduces h1 into LDS.
// Phase 3: layer-2 edge aggregation -> block partials.  [barrier 1]
// Phase 4: block 0 alone: h2, SortPool, convs, FCs -> out.
// ---------------------------------------------------------------------------
__global__ __launch_bounds__(256) void k_rest(
    const int* __restrict__ eidx, const float* __restrict__ eattr,
    double* __restrict__ ws,
    const float* __restrict__ b1, const float* __restrict__ W2, const float* __restrict__ b2,
    const float* __restrict__ c1w, const float* __restrict__ c1b,
    const float* __restrict__ c2w, const float* __restrict__ c2b,
    const float* __restrict__ f1W, const float* __restrict__ f1b,
    const float* __restrict__ f2W, const float* __restrict__ f2b,
    const float* __restrict__ f3W, const float* __restrict__ f3b,
    float* __restrict__ out)
{
    __shared__ double sxw[NN];
    __shared__ double sdinv[3][NN];
    __shared__ double sh1[3][NN];
    __shared__ double hp[4][3][NN];
    // final-phase (block 0 only)
    __shared__ double h2f[3][NN];
    __shared__ double z0[3][NN], z1[3][NN];
    __shared__ int    rnk[3][NN];
    __shared__ double c1o[3][3][127];
    __shared__ double p1o[3][3][125];
    __shared__ double c2o[3][123];
    __shared__ double allx[363];
    __shared__ double fc1o[32], fc2o[6];

    const int b = blockIdx.x, tid = threadIdx.x, wave = tid >> 6;
    unsigned* bar = (unsigned*)(ws + OFF_BAR);
    const int* row = eidx;
    const int* col = eidx + EE;

    // ---- Phase 0: xw + dinv (redundant per block; L2-warm reads)
    for (int j = tid; j < NN; j += 256) {
        double s = 0.0;
#pragma unroll
        for (int k = 0; k < CHUNKS; ++k) s += ws[OFF_PARTIAL + j * CHUNKS + k];
        sxw[j] = s;
    }
    for (int v = tid; v < 3 * NN; v += 256) {
        double d = 1.0;                                  // self loop weight
#pragma unroll
        for (int k = 0; k < NB; ++k) d += ws[OFF_DEGP + k * (3 * NN) + v];
        ((double*)sdinv)[v] = (d > 0.0) ? 1.0 / sqrt(d) : 0.0;
    }
    for (int i = tid; i < 4 * 3 * NN; i += 256) ((double*)hp)[i] = 0.0;
    __syncthreads();

    // ---- Phase 1: layer-1 aggregation over this block's edges
#pragma unroll
    for (int i = 0; i < EPB / 256; ++i) {
        const int e = b * EPB + i * 256 + tid;
        const int r = row[e], cl = col[e];
        const double xwr = sxw[r];
#pragma unroll
        for (int c = 0; c < 3; ++c) {
            const double nw = sdinv[c][r] * (double)eattr[e * 3 + c] * sdinv[c][cl];
            unsafeAtomicAdd(&hp[wave][c][cl], nw * xwr);
        }
    }
    __syncthreads();
    for (int i = tid; i < 3 * NN; i += 256) {
        const int c = i / NN, j = i % NN;
        ws[OFF_H1P + b * (3 * NN) + i] =
            (hp[0][c][j] + hp[1][c][j]) + (hp[2][c][j] + hp[3][c][j]);
    }
    gbar(bar, 0);

    // ---- Phase 2: h1 (redundant per block)
    const double bb1 = (double)b1[0];
    for (int i = tid; i < 3 * NN; i += 256) {
        const int j = i % NN;
        const double dv = ((double*)sdinv)[i];
        double s = dv * dv * sxw[j] + bb1;
#pragma unroll
        for (int k = 0; k < NB; ++k) s += ws[OFF_H1P + k * (3 * NN) + i];
        ((double*)sh1)[i] = s;
    }
    for (int i = tid; i < 4 * 3 * NN; i += 256) ((double*)hp)[i] = 0.0;
    __syncthreads();

    // ---- Phase 3: layer-2 aggregation (input h1*w2; same norms)
    const double w2 = (double)W2[0];
#pragma unroll
    for (int i = 0; i < EPB / 256; ++i) {
        const int e = b * EPB + i * 256 + tid;
        const int r = row[e], cl = col[e];
#pragma unroll
        for (int c = 0; c < 3; ++c) {
            const double nw = sdinv[c][r] * (double)eattr[e * 3 + c] * sdinv[c][cl];
            unsafeAtomicAdd(&hp[wave][c][cl], nw * (sh1[c][r] * w2));
        }
    }
    __syncthreads();
    for (int i = tid; i < 3 * NN; i += 256) {
        const int c = i / NN, j = i % NN;
        ws[OFF_H2P + b * (3 * NN) + i] =
            (hp[0][c][j] + hp[1][c][j]) + (hp[2][c][j] + hp[3][c][j]);
    }
    gbar(bar, 1);

    // ---- Phase 4: block 0 finishes the network
    if (b != 0) return;

    const double bb2 = (double)b2[0];
    for (int i = tid; i < 3 * NN; i += 256) {
        const int j = i % NN;
        const double dv = ((double*)sdinv)[i];
        double s = dv * dv * (((double*)sh1)[i] * w2) + bb2;
#pragma unroll
        for (int k = 0; k < NB; ++k) s += ws[OFF_H2P + k * (3 * NN) + i];
        ((double*)h2f)[i] = s;
    }
    __syncthreads();

    // SortPool: stable argsort of -h2 (descending, ties by index), k = N
    for (int i = tid; i < 3 * NN; i += 256) {
        const int c = i / NN, j = i % NN;
        const double v = h2f[c][j];
        int rk = 0;
        for (int q = 0; q < NN; ++q) {
            const double u = h2f[c][q];
            rk += (u > v) || (u == v && q < j);
        }
        rnk[c][j] = rk;
    }
    __syncthreads();
    for (int i = tid; i < 3 * NN; i += 256) {
        const int c = i / NN, j = i % NN;
        const int rk = rnk[c][j];
        z0[c][rk] = sh1[c][j];
        z1[c][rk] = h2f[c][j];
    }
    __syncthreads();

    // conv1 (in=2,out=3,k=3, VALID) -> 127
    for (int i = tid; i < 3 * 3 * 127; i += 256) {
        const int c = i / (3 * 127), rem = i % (3 * 127), o = rem / 127, p = rem % 127;
        double s = (double)c1b[o];
#pragma unroll
        for (int k = 0; k < 3; ++k) {
            s += (double)c1w[(o * 2 + 0) * 3 + k] * z0[c][p + k];
            s += (double)c1w[(o * 2 + 1) * 3 + k] * z1[c][p + k];
        }
        c1o[c][o][p] = s;
    }
    __syncthreads();
    for (int i = tid; i < 3 * 3 * 125; i += 256) {
        const int c = i / (3 * 125), rem = i % (3 * 125), o = rem / 125, p = rem % 125;
        p1o[c][o][p] = fmax(c1o[c][o][p], fmax(c1o[c][o][p + 1], c1o[c][o][p + 2]));
    }
    __syncthreads();
    for (int i = tid; i < 3 * 123; i += 256) {
        const int c = i / 123, p = i % 123;
        double s = (double)c2b[0];
#pragma unroll
        for (int ic = 0; ic < 3; ++ic)
#pragma unroll
            for (int k = 0; k < 3; ++k)
                s += (double)c2w[ic * 3 + k] * p1o[c][ic][p + k];
        c2o[c][p] = s;
    }
    __syncthreads();
    for (int i = tid; i < 3 * 121; i += 256) {
        const int c = i / 121, p = i % 121;
        allx[c * 121 + p] = fmax(c2o[c][p], fmax(c2o[c][p + 1], c2o[c][p + 2]));
    }
    __syncthreads();

    // fc1: 363 -> 32, ELU (8 lanes per output, aligned subgroups)
    {
        const int j = tid >> 3, t = tid & 7;
        double s = 0.0;
        for (int i = t; i < 363; i += 8) s += allx[i] * (double)f1W[i * 32 + j];
        s += __shfl_down(s, 4, 8);
        s += __shfl_down(s, 2, 8);
        s += __shfl_down(s, 1, 8);
        if (t == 0) {
            s += (double)f1b[j];
            fc1o[j] = (s > 0.0) ? s : expm1(s);
        }
    }
    __syncthreads();
    if (tid < 6) {
        double s = (double)f2b[tid];
        for (int i = 0; i < 32; ++i) s += fc1o[i] * (double)f2W[i * 6 + tid];
        fc2o[tid] = (s > 0.0) ? s : expm1(s);
    }
    __syncthreads();
    if (tid < 2) {
        double s = (double)f3b[tid];
        for (int i = 0; i < 6; ++i) s += fc2o[i] * (double)f3W[i * 2 + tid];
        out[tid] = (float)s;
    }
}

extern "C" void kernel_launch(void* const* d_in, const int* in_sizes, int n_in,
                              void* d_out, int out_size, void* d_ws, size_t ws_size,
                              hipStream_t stream) {
    const float* x    = (const float*)d_in[0];
    const int*   eidx = (const int*)d_in[1];
    const float* eattr= (const float*)d_in[2];
    const float* g1W  = (const float*)d_in[3];
    const float* g1b  = (const float*)d_in[4];
    const float* g2W  = (const float*)d_in[5];
    const float* g2b  = (const float*)d_in[6];
    const float* c1w  = (const float*)d_in[7];
    const float* c1b  = (const float*)d_in[8];
    const float* c2w  = (const float*)d_in[9];
    const float* c2b  = (const float*)d_in[10];
    const float* f1W  = (const float*)d_in[11];
    const float* f1b  = (const float*)d_in[12];
    const float* f2W  = (const float*)d_in[13];
    const float* f2b  = (const float*)d_in[14];
    const float* f3W  = (const float*)d_in[15];
    const float* f3b  = (const float*)d_in[16];
    float* out = (float*)d_out;
    double* ws = (double*)d_ws;

    k_matvec<<<NN * CHUNKS + NB, 256, 0, stream>>>(x, g1W, eidx, eattr, ws);
    k_rest<<<NB, 256, 0, stream>>>(eidx, eattr, ws,
                                   g1b, g2W, g2b, c1w, c1b, c2w, c2b,
                                   f1W, f1b, f2W, f2b, f3W, f3b, out);
}

// Round 4
// 255.952 us; speedup vs baseline: 1.3003x; 1.0360x over previous
//
#include <hip/hip_runtime.h>
#include <hip/hip_bf16.h>
#include <math.h>

// Problem constants (fixed by the reference)
#define NN 129
#define FF 262144
#define EE 16384
#define CHUNKS 32
#define CHUNK (FF / CHUNKS)   // 8192 floats per matvec block
#define NB 16                 // tail-kernel blocks (== degree partial blocks)
#define EPB (EE / NB)         // 1024 edges per block
#define EPT (EPB / 256)       // 4 edges per thread in tail blocks

// ws layout (doubles)
#define OFF_PARTIAL 0                              // [NN*CHUNKS] = 4128
#define OFF_DEGP    (OFF_PARTIAL + NN*CHUNKS)      // [NB*3*NN]
#define OFF_H1P     (OFF_DEGP + NB*3*NN)           // [NB*3*NN]
#define OFF_H2P     (OFF_H1P + NB*3*NN)            // [NB*3*NN]
#define OFF_BAR     (OFF_H2P + NB*3*NN)            // 2 uints (in a double slot)

typedef float vfloat4 __attribute__((ext_vector_type(4)));

// ---------------------------------------------------------------------------
// K1: matvec partials (4128 blocks) + NB blocks of per-block degree partials.
// x is streamed with NON-TEMPORAL loads so the 135 MB stream doesn't evict W
// (1 MB, reused 129x) from the per-XCD L2s — avoids ~134 MB of extra HBM
// fetch (W re-miss every row).
// ---------------------------------------------------------------------------
__global__ __launch_bounds__(256) void k_matvec(
    const float* __restrict__ x, const float* __restrict__ W,
    const int* __restrict__ eidx, const float* __restrict__ eattr,
    double* __restrict__ ws)
{
    const int b = blockIdx.x;
    const int tid = threadIdx.x;
    const int wave = tid >> 6, lane = tid & 63;

    __shared__ double ws4[4];
    __shared__ double dp[4][3][NN];

    if (b < NN * CHUNKS) {
        const int r = b / CHUNKS, ch = b % CHUNKS;
        const vfloat4* xp = (const vfloat4*)(x + (size_t)r * FF + (size_t)ch * CHUNK);
        const float4*  wp = (const float4*)(W + (size_t)ch * CHUNK);
        double acc = 0.0;
#pragma unroll
        for (int i = 0; i < CHUNK / (256 * 4); ++i) {   // 8 iters
            vfloat4 xv = __builtin_nontemporal_load(xp + tid + i * 256);  // nt: bypass L2 allocate
            float4  wv = wp[tid + i * 256];                               // normal: stay L2-hot
            acc += (double)xv[0] * (double)wv.x + (double)xv[1] * (double)wv.y
                 + (double)xv[2] * (double)wv.z + (double)xv[3] * (double)wv.w;
        }
        for (int off = 32; off > 0; off >>= 1) acc += __shfl_down(acc, off, 64);
        if (lane == 0) ws4[wave] = acc;
        __syncthreads();
        if (tid == 0) ws[OFF_PARTIAL + b] = (ws4[0] + ws4[1]) + (ws4[2] + ws4[3]);
    } else {
        const int bb = b - NN * CHUNKS;                 // [0, NB)
        if (bb == 0 && tid == 0) {
            unsigned* bar = (unsigned*)(ws + OFF_BAR);
            __hip_atomic_store(&bar[0], 0u, __ATOMIC_RELAXED, __HIP_MEMORY_SCOPE_AGENT);
            __hip_atomic_store(&bar[1], 0u, __ATOMIC_RELAXED, __HIP_MEMORY_SCOPE_AGENT);
        }
        for (int i = tid; i < 4 * 3 * NN; i += 256) ((double*)dp)[i] = 0.0;
        __syncthreads();
        const int* col = eidx + EE;
#pragma unroll
        for (int i = 0; i < EPT; ++i) {                 // 4 iters
            const int e = bb * EPB + i * 256 + tid;
            const int cl = col[e];
#pragma unroll
            for (int c = 0; c < 3; ++c)
                unsafeAtomicAdd(&dp[wave][c][cl], (double)eattr[e * 3 + c]);
        }
        __syncthreads();
        for (int i = tid; i < 3 * NN; i += 256) {
            const int c = i / NN, j = i % NN;
            ws[OFF_DEGP + bb * (3 * NN) + i] =
                (dp[0][c][j] + dp[1][c][j]) + (dp[2][c][j] + dp[3][c][j]);
        }
    }
}

// ---------------------------------------------------------------------------
// Device-scope barrier for NB co-resident blocks (counters zeroed by K1).
// ---------------------------------------------------------------------------
__device__ __forceinline__ void gbar(unsigned* bar, int idx) {
    __syncthreads();
    if (threadIdx.x == 0) {
        __threadfence();
        __hip_atomic_fetch_add(&bar[idx], 1u, __ATOMIC_ACQ_REL, __HIP_MEMORY_SCOPE_AGENT);
        while (__hip_atomic_load(&bar[idx], __ATOMIC_ACQUIRE, __HIP_MEMORY_SCOPE_AGENT) < (unsigned)NB)
            __builtin_amdgcn_s_sleep(1);
        __threadfence();
    }
    __syncthreads();
}

// ---------------------------------------------------------------------------
// K2 (NB blocks, manual grid barriers): entire rest of the network.
// Kept as a separate kernel ON PURPOSE: its ~55 KB LDS would otherwise be
// charged to every matvec block and cap the streaming kernel at 2 blocks/CU.
// ---------------------------------------------------------------------------
__global__ __launch_bounds__(256) void k_rest(
    const int* __restrict__ eidx, const float* __restrict__ eattr,
    double* __restrict__ ws,
    const float* __restrict__ b1, const float* __restrict__ W2, const float* __restrict__ b2,
    const float* __restrict__ c1w, const float* __restrict__ c1b,
    const float* __restrict__ c2w, const float* __restrict__ c2b,
    const float* __restrict__ f1W, const float* __restrict__ f1b,
    const float* __restrict__ f2W, const float* __restrict__ f2b,
    const float* __restrict__ f3W, const float* __restrict__ f3b,
    float* __restrict__ out)
{
    __shared__ double sxw[NN];
    __shared__ double sdinv[3][NN];
    __shared__ double sh1[3][NN];
    __shared__ double hp[4][3][NN];
    // final-phase (block 0 only)
    __shared__ double h2f[3][NN];
    __shared__ double z0[3][NN], z1[3][NN];
    __shared__ int    rnk[3][NN];
    __shared__ double c1o[3][3][127];
    __shared__ double p1o[3][3][125];
    __shared__ double c2o[3][123];
    __shared__ double allx[363];
    __shared__ double fc1o[32], fc2o[6];

    const int b = blockIdx.x, tid = threadIdx.x, wave = tid >> 6;
    unsigned* bar = (unsigned*)(ws + OFF_BAR);
    const int* row = eidx;
    const int* col = eidx + EE;

    // ---- Phase 0: xw + dinv (redundant per block; L2-warm reads)
    for (int j = tid; j < NN; j += 256) {
        double s = 0.0;
#pragma unroll
        for (int k = 0; k < CHUNKS; ++k) s += ws[OFF_PARTIAL + j * CHUNKS + k];
        sxw[j] = s;
    }
    for (int v = tid; v < 3 * NN; v += 256) {
        double d = 1.0;                                  // self loop weight
#pragma unroll
        for (int k = 0; k < NB; ++k) d += ws[OFF_DEGP + k * (3 * NN) + v];
        ((double*)sdinv)[v] = (d > 0.0) ? 1.0 / sqrt(d) : 0.0;
    }
    for (int i = tid; i < 4 * 3 * NN; i += 256) ((double*)hp)[i] = 0.0;
    __syncthreads();

    // ---- Phase 1: layer-1 aggregation; cache edges + norms in registers
    int er[EPT], ec[EPT];
    double enw[EPT][3];
#pragma unroll
    for (int i = 0; i < EPT; ++i) {
        const int e = b * EPB + i * 256 + tid;
        const int r = row[e], cl = col[e];
        er[i] = r; ec[i] = cl;
        const double xwr = sxw[r];
#pragma unroll
        for (int c = 0; c < 3; ++c) {
            const double nw = sdinv[c][r] * (double)eattr[e * 3 + c] * sdinv[c][cl];
            enw[i][c] = nw;
            unsafeAtomicAdd(&hp[wave][c][cl], nw * xwr);
        }
    }
    __syncthreads();
    for (int i = tid; i < 3 * NN; i += 256) {
        const int c = i / NN, j = i % NN;
        ws[OFF_H1P + b * (3 * NN) + i] =
            (hp[0][c][j] + hp[1][c][j]) + (hp[2][c][j] + hp[3][c][j]);
    }
    gbar(bar, 0);

    // ---- Phase 2: h1 (redundant per block)
    const double bb1 = (double)b1[0];
    for (int i = tid; i < 3 * NN; i += 256) {
        const int j = i % NN;
        const double dv = ((double*)sdinv)[i];
        double s = dv * dv * sxw[j] + bb1;
#pragma unroll
        for (int k = 0; k < NB; ++k) s += ws[OFF_H1P + k * (3 * NN) + i];
        ((double*)sh1)[i] = s;
    }
    for (int i = tid; i < 4 * 3 * NN; i += 256) ((double*)hp)[i] = 0.0;
    __syncthreads();

    // ---- Phase 3: layer-2 aggregation (register-cached norms; same edges)
    const double w2 = (double)W2[0];
#pragma unroll
    for (int i = 0; i < EPT; ++i) {
        const int r = er[i], cl = ec[i];
#pragma unroll
        for (int c = 0; c < 3; ++c)
            unsafeAtomicAdd(&hp[wave][c][cl], enw[i][c] * (sh1[c][r] * w2));
    }
    __syncthreads();
    for (int i = tid; i < 3 * NN; i += 256) {
        const int c = i / NN, j = i % NN;
        ws[OFF_H2P + b * (3 * NN) + i] =
            (hp[0][c][j] + hp[1][c][j]) + (hp[2][c][j] + hp[3][c][j]);
    }
    gbar(bar, 1);

    // ---- Phase 4: block 0 finishes the network
    if (b != 0) return;

    const double bb2 = (double)b2[0];
    for (int i = tid; i < 3 * NN; i += 256) {
        const int j = i % NN;
        const double dv = ((double*)sdinv)[i];
        double s = dv * dv * (((double*)sh1)[i] * w2) + bb2;
#pragma unroll
        for (int k = 0; k < NB; ++k) s += ws[OFF_H2P + k * (3 * NN) + i];
        ((double*)h2f)[i] = s;
    }
    __syncthreads();

    // SortPool: stable argsort of -h2 (descending, ties by index), k = N
    for (int i = tid; i < 3 * NN; i += 256) {
        const int c = i / NN, j = i % NN;
        const double v = h2f[c][j];
        int rk = 0;
        for (int q = 0; q < NN; ++q) {
            const double u = h2f[c][q];
            rk += (u > v) || (u == v && q < j);
        }
        rnk[c][j] = rk;
    }
    __syncthreads();
    for (int i = tid; i < 3 * NN; i += 256) {
        const int c = i / NN, j = i % NN;
        const int rk = rnk[c][j];
        z0[c][rk] = sh1[c][j];
        z1[c][rk] = h2f[c][j];
    }
    __syncthreads();

    // conv1 (in=2,out=3,k=3, VALID) -> 127
    for (int i = tid; i < 3 * 3 * 127; i += 256) {
        const int c = i / (3 * 127), rem = i % (3 * 127), o = rem / 127, p = rem % 127;
        double s = (double)c1b[o];
#pragma unroll
        for (int k = 0; k < 3; ++k) {
            s += (double)c1w[(o * 2 + 0) * 3 + k] * z0[c][p + k];
            s += (double)c1w[(o * 2 + 1) * 3 + k] * z1[c][p + k];
        }
        c1o[c][o][p] = s;
    }
    __syncthreads();
    for (int i = tid; i < 3 * 3 * 125; i += 256) {
        const int c = i / (3 * 125), rem = i % (3 * 125), o = rem / 125, p = rem % 125;
        p1o[c][o][p] = fmax(c1o[c][o][p], fmax(c1o[c][o][p + 1], c1o[c][o][p + 2]));
    }
    __syncthreads();
    for (int i = tid; i < 3 * 123; i += 256) {
        const int c = i / 123, p = i % 123;
        double s = (double)c2b[0];
#pragma unroll
        for (int ic = 0; ic < 3; ++ic)
#pragma unroll
            for (int k = 0; k < 3; ++k)
                s += (double)c2w[ic * 3 + k] * p1o[c][ic][p + k];
        c2o[c][p] = s;
    }
    __syncthreads();
    for (int i = tid; i < 3 * 121; i += 256) {
        const int c = i / 121, p = i % 121;
        allx[c * 121 + p] = fmax(c2o[c][p], fmax(c2o[c][p + 1], c2o[c][p + 2]));
    }
    __syncthreads();

    // fc1: 363 -> 32, ELU (8 lanes per output, aligned subgroups)
    {
        const int j = tid >> 3, t = tid & 7;
        double s = 0.0;
        for (int i = t; i < 363; i += 8) s += allx[i] * (double)f1W[i * 32 + j];
        s += __shfl_down(s, 4, 8);
        s += __shfl_down(s, 2, 8);
        s += __shfl_down(s, 1, 8);
        if (t == 0) {
            s += (double)f1b[j];
            fc1o[j] = (s > 0.0) ? s : expm1(s);
        }
    }
    __syncthreads();
    if (tid < 6) {
        double s = (double)f2b[tid];
        for (int i = 0; i < 32; ++i) s += fc1o[i] * (double)f2W[i * 6 + tid];
        fc2o[tid] = (s > 0.0) ? s : expm1(s);
    }
    __syncthreads();
    if (tid < 2) {
        double s = (double)f3b[tid];
        for (int i = 0; i < 6; ++i) s += fc2o[i] * (double)f3W[i * 2 + tid];
        out[tid] = (float)s;
    }
}

extern "C" void kernel_launch(void* const* d_in, const int* in_sizes, int n_in,
                              void* d_out, int out_size, void* d_ws, size_t ws_size,
                              hipStream_t stream) {
    const float* x    = (const float*)d_in[0];
    const int*   eidx = (const int*)d_in[1];
    const float* eattr= (const float*)d_in[2];
    const float* g1W  = (const float*)d_in[3];
    const float* g1b  = (const float*)d_in[4];
    const float* g2W  = (const float*)d_in[5];
    const float* g2b  = (const float*)d_in[6];
    const float* c1w  = (const float*)d_in[7];
    const float* c1b  = (const float*)d_in[8];
    const float* c2w  = (const float*)d_in[9];
    const float* c2b  = (const float*)d_in[10];
    const float* f1W  = (const float*)d_in[11];
    const float* f1b  = (const float*)d_in[12];
    const float* f2W  = (const float*)d_in[13];
    const float* f2b  = (const float*)d_in[14];
    const float* f3W  = (const float*)d_in[15];
    const float* f3b  = (const float*)d_in[16];
    float* out = (float*)d_out;
    double* ws = (double*)d_ws;

    k_matvec<<<NN * CHUNKS + NB, 256, 0, stream>>>(x, g1W, eidx, eattr, ws);
    k_rest<<<NB, 256, 0, stream>>>(eidx, eattr, ws,
                                   g1b, g2W, g2b, c1w, c1b, c2w, c2b,
                                   f1W, f1b, f2W, f2b, f3W, f3b, out);
}